// Round 7
// baseline (219.659 us; speedup 1.0000x reference)
//
#include <hip/hip_runtime.h>
#include <stdint.h>

#define T_DIM 64
#define A_DIM 64
#define F_DIM 512
#define H_DIM 1024
#define N_DIM 512
#define E_DIM 4
#define NTOK 4096
#define NTOK_PAD 4224   // +128 rows slack so 64-row tiles can over-read
#define NSLOT 72        // >= max sum_e ceil(cnt_e/64) = 67, and NSLOT*NT % 8 == 0

typedef __attribute__((ext_vector_type(8))) short short8;
typedef __attribute__((ext_vector_type(4))) short short4v;
typedef __attribute__((ext_vector_type(4))) float f32x4;

// ---------- bf16 helpers (RNE) ----------
__device__ __forceinline__ unsigned short f2bf(float x) {
  unsigned u = __float_as_uint(x);
  u += 0x7fffu + ((u >> 16) & 1u);
  return (unsigned short)(u >> 16);
}
__device__ __forceinline__ float bf2f(unsigned short h) {
  return __uint_as_float(((unsigned)h) << 16);
}
__device__ __forceinline__ void split_bf(float x, short& hi, short& lo) {
  unsigned short h = f2bf(x);
  hi = (short)h;
  lo = (short)f2bf(x - bf2f(h));
}

// ---------- async global->LDS, 16B per lane ----------
__device__ __forceinline__ void gload_lds16(const void* g, void* l) {
  __builtin_amdgcn_global_load_lds(
      (const __attribute__((address_space(1))) unsigned int*)g,
      (__attribute__((address_space(3))) unsigned int*)l, 16, 0, 0);
}

// ---------- routing: histogram + prefix + per-token position + slot worklist ----------
__global__ __launch_bounds__(1024) void k_route(const int* __restrict__ at,
                                                int* __restrict__ pos,
                                                int4* __restrict__ slots) {
  __shared__ int wt[16][4];
  __shared__ int woff[16][4];
  __shared__ int soff[4];
  int tid = threadIdx.x;
  int w = tid >> 6, ln = tid & 63;

  int4 a = ((const int4*)at)[tid];
  int c[4] = {0, 0, 0, 0};
  c[a.x]++; c[a.y]++; c[a.z]++; c[a.w]++;

  int inc[4];
#pragma unroll
  for (int e = 0; e < 4; ++e) inc[e] = c[e];
#pragma unroll
  for (int d = 1; d < 64; d <<= 1) {
#pragma unroll
    for (int e = 0; e < 4; ++e) {
      int u = __shfl_up(inc[e], d, 64);
      if (ln >= d) inc[e] += u;
    }
  }
  if (ln == 63) {
#pragma unroll
    for (int e = 0; e < 4; ++e) wt[w][e] = inc[e];
  }
  __syncthreads();
  if (tid == 0) {
    int tot[4] = {0, 0, 0, 0};
    for (int i = 0; i < 16; ++i)
      for (int e = 0; e < 4; ++e) { woff[i][e] = tot[e]; tot[e] += wt[i][e]; }
    int acc = 0;
    int sbase[4];
    for (int e = 0; e < 4; ++e) { sbase[e] = acc; soff[e] = acc; acc += tot[e]; }
    int si = 0;
    for (int e = 0; e < 4; ++e) {
      int cnt = tot[e];
      for (int m = 0; m * 64 < cnt; ++m) {
        int4 s;
        s.x = sbase[e] + m * 64;
        s.y = (cnt - m * 64) < 64 ? (cnt - m * 64) : 64;
        s.z = e; s.w = 0;
        slots[si++] = s;
      }
    }
    int4 z; z.x = 0; z.y = 0; z.z = 0; z.w = 0;
    while (si < NSLOT) slots[si++] = z;
  }
  __syncthreads();
  int excl[4];
#pragma unroll
  for (int e = 0; e < 4; ++e) excl[e] = soff[e] + woff[w][e] + inc[e] - c[e];
  int es[4] = {a.x, a.y, a.z, a.w};
#pragma unroll
  for (int k = 0; k < 4; ++k) {
    int e = es[k];
    pos[tid * 4 + k] = excl[e];
    excl[e]++;
  }
}

// ---------- fused prep: gather (blocks 0..1023) + 3x weight transpose/split ----------
__device__ __forceinline__ void wsplit_tile(const float* __restrict__ W,
                                            short* __restrict__ Th,
                                            short* __restrict__ Tl,
                                            int K, int N, int e, int n0, int k0,
                                            float (*tile)[65]) {
  const float* w = W + (size_t)e * K * N;
  int tr = threadIdx.x >> 4;
  int tc = threadIdx.x & 15;
#pragma unroll
  for (int i = 0; i < 4; ++i) {
    int kk = k0 + i * 16 + tr;
    float4 v = *(const float4*)(w + (size_t)kk * N + n0 + tc * 4);
    tile[i * 16 + tr][tc * 4 + 0] = v.x;
    tile[i * 16 + tr][tc * 4 + 1] = v.y;
    tile[i * 16 + tr][tc * 4 + 2] = v.z;
    tile[i * 16 + tr][tc * 4 + 3] = v.w;
  }
  __syncthreads();
#pragma unroll
  for (int i = 0; i < 4; ++i) {
    int nr = i * 16 + tr;
    size_t ob = ((size_t)e * N + (n0 + nr)) * K + k0 + tc * 4;
    short4v hh, ll;
#pragma unroll
    for (int j = 0; j < 4; ++j) {
      float x = tile[tc * 4 + j][nr];
      short h, l;
      split_bf(x, h, l);
      hh[j] = h; ll[j] = l;
    }
    *(short4v*)&Th[ob] = hh;
    *(short4v*)&Tl[ob] = ll;
  }
}

// grid = 1024 (gather) + 512 (W1) + 1024 (W2) + 512 (W3) = 3072 blocks x 256
__global__ __launch_bounds__(256) void k_prep(
    const float* __restrict__ obs, const int* __restrict__ pos, int* __restrict__ idx,
    short* __restrict__ oH, short* __restrict__ oL,
    const float* __restrict__ W1, short* __restrict__ w1h, short* __restrict__ w1l,
    const float* __restrict__ W2, short* __restrict__ w2h, short* __restrict__ w2l,
    const float* __restrict__ W3, short* __restrict__ w3h, short* __restrict__ w3l) {
  __shared__ float tile[64][65];
  int b = blockIdx.x;
  if (b < 1024) {
    // gather: 4 tokens per block
    int tid = threadIdx.x;
    int t = b * 4 + (tid >> 6);
    int ln = tid & 63;
    int p = pos[t];
    if (ln == 0) idx[p] = t;
    const float* src = obs + (size_t)t * F_DIM;
    int base = ln * 8;
    float4 v0 = *(const float4*)(src + base);
    float4 v1 = *(const float4*)(src + base + 4);
    float xs[8] = {v0.x, v0.y, v0.z, v0.w, v1.x, v1.y, v1.z, v1.w};
    short8 hh, ll;
#pragma unroll
    for (int i = 0; i < 8; ++i) {
      short h, l;
      split_bf(xs[i], h, l);
      hh[i] = h; ll[i] = l;
    }
    *(short8*)&oH[(size_t)p * F_DIM + base] = hh;
    *(short8*)&oL[(size_t)p * F_DIM + base] = ll;
  } else if (b < 1536) {
    // W1: K=512 (8 k-tiles), N=1024 (16 n-tiles), 4 experts
    int i = b - 1024;
    int e = i >> 7, r = i & 127;           // 128 tiles/expert
    int n0 = (r >> 3) * 64, k0 = (r & 7) * 64;
    wsplit_tile(W1, w1h, w1l, F_DIM, H_DIM, e, n0, k0, tile);
  } else if (b < 2560) {
    // W2: 16 x 16 tiles, 4 experts
    int i = b - 1536;
    int e = i >> 8, r = i & 255;
    int n0 = (r >> 4) * 64, k0 = (r & 15) * 64;
    wsplit_tile(W2, w2h, w2l, H_DIM, H_DIM, e, n0, k0, tile);
  } else {
    // W3: K=1024 (16 k-tiles), N=512 (8 n-tiles), 4 experts
    int i = b - 2560;
    int e = i >> 7, r = i & 127;
    int n0 = (r >> 4) * 64, k0 = (r & 15) * 64;
    wsplit_tile(W3, w3h, w3l, H_DIM, N_DIM, e, n0, k0, tile);
  }
}

// ---------- grouped GEMM: 64x128 tile, 4 waves (2x2) ----------
// 3-buffer LDS pipeline, counted vmcnt(6) in steady state (T3/T4); the FINAL
// K-step has no younger stage in flight -> must drain vmcnt(0) (derived-wait
// epilogue; vmcnt(6) there would be a no-op and race the last buffer).
// Bank swizzle: LDS dest linear (global_load_lds constraint); global SOURCE
// chunk pre-swizzled lch=(wc&3)^((wc>>3)&3); reads apply same XOR (involution).
// split product: ah*bh + ah*bl + al*bh (~2^-16 relative)
template <int K, int NOUT, bool RELU, bool FINAL>
__launch_bounds__(256, 2)
__global__ void k_gemm(const short* __restrict__ Ah, const short* __restrict__ Al,
                       const short* __restrict__ Bh, const short* __restrict__ Bl,
                       const float* __restrict__ bias,
                       short* __restrict__ Ch, short* __restrict__ Cl,
                       float* __restrict__ outF, const int* __restrict__ idx,
                       const int4* __restrict__ slots) {
  constexpr int NT  = NOUT / 128;
  constexpr int NWG = NSLOT * NT;
  int wg   = (blockIdx.x & 7) * (NWG / 8) + (blockIdx.x >> 3);
  int slot = wg / NT;
  int nt   = wg % NT;
  int4 s = slots[slot];
  int rows = s.y;
  if (rows == 0) return;
  int row0 = s.x, e = s.z, row_end = row0 + rows;
  int ncol0 = nt * 128;

  // per buffer (shorts): [Ah 64x32 @0][Al @2048][Bh 128x32 @4096][Bl @8192] = 24 KiB; x3 = 72 KiB
  __shared__ short lds[3][12288];

  int tid = threadIdx.x, wave = tid >> 6, ln = tid & 63;
  const short* bPh = Bh + (size_t)e * NOUT * K;
  const short* bPl = Bl + (size_t)e * NOUT * K;

  // 6 loop-invariant staging source pointers (16B chunk per lane), source pre-swizzled
  const short* srcb[6];
#pragma unroll
  for (int r = 0; r < 6; ++r) {
    int g = r * 256 + tid;
    const short* plane; int wc, rb;
    if (g < 256)       { plane = Ah;  wc = g;        rb = row0;  }
    else if (g < 512)  { plane = Al;  wc = g - 256;  rb = row0;  }
    else if (g < 1024) { plane = bPh; wc = g - 512;  rb = ncol0; }
    else               { plane = bPl; wc = g - 1024; rb = ncol0; }
    int prow = wc >> 2;
    int lch  = (wc & 3) ^ ((wc >> 3) & 3);   // inverse(=same) of read-side XOR
    srcb[r] = plane + (size_t)(rb + prow) * K + lch * 8;
  }

  // LDS dest is wave-uniform base (+ lane*16 applied by HW) [m104/m108]
  int wbase = (tid & ~63) * 8;

  auto stage = [&](int buf, int ks) {
    int k0 = ks * 32;
#pragma unroll
    for (int r = 0; r < 6; ++r)
      gload_lds16(srcb[r] + k0, (void*)&lds[buf][r * 2048 + wbase]);
  };

  f32x4 acc[2][4] = {};
  int wr = wave >> 1, wcn = wave & 1;
  int tm = ln & 15, kg = ln >> 4;

  // read-side swizzled short-offsets (loop-invariant)
  int aoff[2], boff[4];
#pragma unroll
  for (int i = 0; i < 2; ++i) {
    int arow = wr * 32 + i * 16 + tm;
    aoff[i] = arow * 32 + (kg ^ ((arow >> 1) & 3)) * 8;
  }
#pragma unroll
  for (int j = 0; j < 4; ++j) {
    int brow = wcn * 64 + j * 16 + tm;
    boff[j] = brow * 32 + (kg ^ ((brow >> 1) & 3)) * 8;
  }

  stage(0, 0);
  stage(1, 1);                       // 12 loads in flight
  constexpr int NK = K / 32;
  int cb = 0, sb = 2;
  for (int ks = 0; ks < NK; ++ks) {
    // derived wait: 6 while a younger stage is in flight; 0 on the final step
    if (ks < NK - 1) {
      asm volatile("s_waitcnt vmcnt(6)" ::: "memory");
    } else {
      asm volatile("s_waitcnt vmcnt(0)" ::: "memory");
    }
    __builtin_amdgcn_s_barrier();
    asm volatile("" ::: "memory");

    short8 ah[2], al[2], bh[4], bl[4];
#pragma unroll
    for (int i = 0; i < 2; ++i) {
      ah[i] = *(const short8*)&lds[cb][aoff[i]];
      al[i] = *(const short8*)&lds[cb][2048 + aoff[i]];
    }
#pragma unroll
    for (int j = 0; j < 4; ++j) {
      bh[j] = *(const short8*)&lds[cb][4096 + boff[j]];
      bl[j] = *(const short8*)&lds[cb][8192 + boff[j]];
    }
#pragma unroll
    for (int i = 0; i < 2; ++i)
#pragma unroll
      for (int j = 0; j < 4; ++j) {
        acc[i][j] = __builtin_amdgcn_mfma_f32_16x16x32_bf16(ah[i], bh[j], acc[i][j], 0, 0, 0);
        acc[i][j] = __builtin_amdgcn_mfma_f32_16x16x32_bf16(ah[i], bl[j], acc[i][j], 0, 0, 0);
        acc[i][j] = __builtin_amdgcn_mfma_f32_16x16x32_bf16(al[i], bh[j], acc[i][j], 0, 0, 0);
      }

    // all waves done reading lds[cb]; the buffer staged NOW was last read
    // 2 barriers ago -> safe
    asm volatile("" ::: "memory");
    __builtin_amdgcn_s_barrier();
    asm volatile("" ::: "memory");
    if (ks + 2 < NK) stage(sb, ks + 2);
    cb = (cb == 2) ? 0 : cb + 1;
    sb = (sb == 2) ? 0 : sb + 1;
  }

  // epilogue: C/D layout col=lane&15, row=(lane>>4)*4+q  [m89-verified]
  int lcol = ln & 15;
  int lrow4 = (ln >> 4) * 4;
#pragma unroll
  for (int j = 0; j < 4; ++j) {
    int col = ncol0 + wcn * 64 + j * 16 + lcol;
    float bv = bias[(size_t)e * NOUT + col];
#pragma unroll
    for (int i = 0; i < 2; ++i) {
      int gr0 = row0 + wr * 32 + i * 16 + lrow4;
#pragma unroll
      for (int q = 0; q < 4; ++q) {
        int grow = gr0 + q;
        if (grow < row_end) {
          float x = acc[i][j][q] + bv;
          if (RELU) x = fmaxf(x, 0.0f);
          if (FINAL) {
            int token = idx[grow];
            outF[(size_t)token * NOUT + col] = x;
          } else {
            short h, l;
            split_bf(x, h, l);
            Ch[(size_t)grow * NOUT + col] = h;
            Cl[(size_t)grow * NOUT + col] = l;
          }
        }
      }
    }
  }
}

extern "C" void kernel_launch(void* const* d_in, const int* in_sizes, int n_in,
                              void* d_out, int out_size, void* d_ws, size_t ws_size,
                              hipStream_t stream) {
  (void)in_sizes; (void)n_in; (void)out_size; (void)ws_size;
  const float* obs = (const float*)d_in[0];
  const float* W1  = (const float*)d_in[1];
  const float* b1  = (const float*)d_in[2];
  const float* W2  = (const float*)d_in[3];
  const float* b2  = (const float*)d_in[4];
  const float* W3  = (const float*)d_in[5];
  const float* b3  = (const float*)d_in[6];
  const int*   at  = (const int*)d_in[7];
  float* out = (float*)d_out;

  char* w = (char*)d_ws;
  auto carve = [&](size_t bytes) {
    char* p = w;
    w += (bytes + 255) & ~(size_t)255;
    return p;
  };
  int*  pos   = (int*)carve(NTOK * 4);
  int4* slots = (int4*)carve(NSLOT * 16);
  int*  idx   = (int*)carve(NTOK_PAD * 4);
  short* obsH = (short*)carve((size_t)NTOK_PAD * F_DIM * 2);
  short* obsL = (short*)carve((size_t)NTOK_PAD * F_DIM * 2);
  short* h1H  = (short*)carve((size_t)NTOK_PAD * H_DIM * 2);
  short* h1L  = (short*)carve((size_t)NTOK_PAD * H_DIM * 2);
  short* h2H  = (short*)carve((size_t)NTOK_PAD * H_DIM * 2);
  short* h2L  = (short*)carve((size_t)NTOK_PAD * H_DIM * 2);
  short* w1h  = (short*)carve((size_t)E_DIM * H_DIM * F_DIM * 2);
  short* w1l  = (short*)carve((size_t)E_DIM * H_DIM * F_DIM * 2);
  short* w2h  = (short*)carve((size_t)E_DIM * H_DIM * H_DIM * 2);
  short* w2l  = (short*)carve((size_t)E_DIM * H_DIM * H_DIM * 2);
  short* w3h  = (short*)carve((size_t)E_DIM * N_DIM * H_DIM * 2);
  short* w3l  = (short*)carve((size_t)E_DIM * N_DIM * H_DIM * 2);

  k_route<<<1, 1024, 0, stream>>>(at, pos, slots);
  k_prep<<<3072, 256, 0, stream>>>(obs, pos, idx, obsH, obsL,
                                   W1, w1h, w1l, W2, w2h, w2l, W3, w3h, w3l);

  k_gemm<F_DIM, H_DIM, true, false>
      <<<NSLOT * (H_DIM / 128), 256, 0, stream>>>(
          obsH, obsL, w1h, w1l, b1, h1H, h1L, nullptr, nullptr, slots);
  k_gemm<H_DIM, H_DIM, true, false>
      <<<NSLOT * (H_DIM / 128), 256, 0, stream>>>(
          h1H, h1L, w2h, w2l, b2, h2H, h2L, nullptr, nullptr, slots);
  k_gemm<H_DIM, N_DIM, false, true>
      <<<NSLOT * (N_DIM / 128), 256, 0, stream>>>(
          h2H, h2L, w3h, w3l, b3, nullptr, nullptr, out, idx, slots);
}

// Round 10
// 192.873 us; speedup vs baseline: 1.1389x; 1.1389x over previous
//
#include <hip/hip_runtime.h>
#include <stdint.h>

#define T_DIM 64
#define A_DIM 64
#define F_DIM 512
#define H_DIM 1024
#define N_DIM 512
#define E_DIM 4
#define NTOK 4096
#define NTOK_PAD 4352   // 68 rowblocks of 64: 4096 + up to 4*63 alignment pad, rounded up
#define NSLOT 72        // >= max sum_e ceil(cnt_e/64) = 67, and NSLOT*NT % 8 == 0

typedef __attribute__((ext_vector_type(8))) short short8;
typedef __attribute__((ext_vector_type(4))) short short4v;
typedef __attribute__((ext_vector_type(4))) float f32x4;

// ---------- bf16 helpers (RNE) ----------
__device__ __forceinline__ unsigned short f2bf(float x) {
  unsigned u = __float_as_uint(x);
  u += 0x7fffu + ((u >> 16) & 1u);
  return (unsigned short)(u >> 16);
}
__device__ __forceinline__ float bf2f(unsigned short h) {
  return __uint_as_float(((unsigned)h) << 16);
}
__device__ __forceinline__ void split_bf(float x, short& hi, short& lo) {
  unsigned short h = f2bf(x);
  hi = (short)h;
  lo = (short)f2bf(x - bf2f(h));
}

// ---------- async global->LDS, 16B per lane ----------
__device__ __forceinline__ void gload_lds16(const void* g, void* l) {
  __builtin_amdgcn_global_load_lds(
      (const __attribute__((address_space(1))) unsigned int*)g,
      (__attribute__((address_space(3))) unsigned int*)l, 16, 0, 0);
}

// ---------- routing: histogram + prefix + per-token position + slot worklist ----------
// Expert segment starts are PADDED to 64-multiples so every GEMM slot row0 is
// 64-aligned (required by the tiled [rowblk64][kt][64][32] operand layout).
__global__ __launch_bounds__(1024) void k_route(const int* __restrict__ at,
                                                int* __restrict__ pos,
                                                int4* __restrict__ slots) {
  __shared__ int wt[16][4];
  __shared__ int woff[16][4];
  __shared__ int soff[4];
  int tid = threadIdx.x;
  int w = tid >> 6, ln = tid & 63;

  int4 a = ((const int4*)at)[tid];
  int c[4] = {0, 0, 0, 0};
  c[a.x]++; c[a.y]++; c[a.z]++; c[a.w]++;

  int inc[4];
#pragma unroll
  for (int e = 0; e < 4; ++e) inc[e] = c[e];
#pragma unroll
  for (int d = 1; d < 64; d <<= 1) {
#pragma unroll
    for (int e = 0; e < 4; ++e) {
      int u = __shfl_up(inc[e], d, 64);
      if (ln >= d) inc[e] += u;
    }
  }
  if (ln == 63) {
#pragma unroll
    for (int e = 0; e < 4; ++e) wt[w][e] = inc[e];
  }
  __syncthreads();
  if (tid == 0) {
    int tot[4] = {0, 0, 0, 0};
    for (int i = 0; i < 16; ++i)
      for (int e = 0; e < 4; ++e) { woff[i][e] = tot[e]; tot[e] += wt[i][e]; }
    int acc = 0;
    int sbase[4];
    for (int e = 0; e < 4; ++e) {
      sbase[e] = acc; soff[e] = acc;
      acc += (tot[e] + 63) & ~63;          // 64-aligned segment starts
    }
    int si = 0;
    for (int e = 0; e < 4; ++e) {
      int cnt = tot[e];
      for (int m = 0; m * 64 < cnt; ++m) {
        int4 s;
        s.x = sbase[e] + m * 64;            // 64-aligned
        s.y = (cnt - m * 64) < 64 ? (cnt - m * 64) : 64;
        s.z = e; s.w = 0;
        slots[si++] = s;
      }
    }
    int4 z; z.x = 0; z.y = 0; z.z = 0; z.w = 0;
    while (si < NSLOT) slots[si++] = z;
  }
  __syncthreads();
  int excl[4];
#pragma unroll
  for (int e = 0; e < 4; ++e) excl[e] = soff[e] + woff[w][e] + inc[e] - c[e];
  int es[4] = {a.x, a.y, a.z, a.w};
#pragma unroll
  for (int k = 0; k < 4; ++k) {
    int e = es[k];
    pos[tid * 4 + k] = excl[e];
    excl[e]++;
  }
}

// ---------- fused prep ----------
// A planes tiled:  [rowblk][kt][64][32]   (2048 shorts per tile)
// B planes tiled:  [e][colblk128][kt][128][32] (4096 shorts per tile)
__device__ __forceinline__ void wsplit_tile(const float* __restrict__ W,
                                            short* __restrict__ Th,
                                            short* __restrict__ Tl,
                                            int K, int N, int NB, int e, int n0,
                                            int k0, float (*tile)[65]) {
  const float* w = W + (size_t)e * K * N;
  int KT = K >> 5;
  int tr = threadIdx.x >> 4;
  int tc = threadIdx.x & 15;
#pragma unroll
  for (int i = 0; i < 4; ++i) {
    int kk = k0 + i * 16 + tr;
    float4 v = *(const float4*)(w + (size_t)kk * N + n0 + tc * 4);
    tile[i * 16 + tr][tc * 4 + 0] = v.x;
    tile[i * 16 + tr][tc * 4 + 1] = v.y;
    tile[i * 16 + tr][tc * 4 + 2] = v.z;
    tile[i * 16 + tr][tc * 4 + 3] = v.w;
  }
  __syncthreads();
#pragma unroll
  for (int i = 0; i < 4; ++i) {
    int nr = i * 16 + tr;
    int n = n0 + nr;
    int k = k0 + tc * 4;
    size_t ob = ((((size_t)e * NB + (n >> 7)) * KT + (k >> 5)) * 128 + (n & 127)) * 32 + (k & 31);
    short4v hh, ll;
#pragma unroll
    for (int j = 0; j < 4; ++j) {
      float x = tile[tc * 4 + j][nr];
      short h, l;
      split_bf(x, h, l);
      hh[j] = h; ll[j] = l;
    }
    *(short4v*)&Th[ob] = hh;
    *(short4v*)&Tl[ob] = ll;
  }
}

// grid = 1024 (gather) + 512 (W1) + 1024 (W2) + 512 (W3) = 3072 blocks x 256
__global__ __launch_bounds__(256) void k_prep(
    const float* __restrict__ obs, const int* __restrict__ pos, int* __restrict__ idx,
    short* __restrict__ oH, short* __restrict__ oL,
    const float* __restrict__ W1, short* __restrict__ w1h, short* __restrict__ w1l,
    const float* __restrict__ W2, short* __restrict__ w2h, short* __restrict__ w2l,
    const float* __restrict__ W3, short* __restrict__ w3h, short* __restrict__ w3l) {
  __shared__ float tile[64][65];
  int b = blockIdx.x;
  if (b < 1024) {
    // gather: 4 tokens per block, write tiled A layout
    int tid = threadIdx.x;
    int t = b * 4 + (tid >> 6);
    int ln = tid & 63;
    int p = pos[t];
    if (ln == 0) idx[p] = t;
    const float* src = obs + (size_t)t * F_DIM;
    int base = ln * 8;
    float4 v0 = *(const float4*)(src + base);
    float4 v1 = *(const float4*)(src + base + 4);
    float xs[8] = {v0.x, v0.y, v0.z, v0.w, v1.x, v1.y, v1.z, v1.w};
    short8 hh, ll;
#pragma unroll
    for (int i = 0; i < 8; ++i) {
      short h, l;
      split_bf(xs[i], h, l);
      hh[i] = h; ll[i] = l;
    }
    size_t tb = ((size_t)(p >> 6) * (F_DIM / 32) + (base >> 5)) * 2048 +
                (size_t)(p & 63) * 32 + (base & 31);
    *(short8*)&oH[tb] = hh;
    *(short8*)&oL[tb] = ll;
  } else if (b < 1536) {
    int i = b - 1024;
    int e = i >> 7, r = i & 127;
    int n0 = (r >> 3) * 64, k0 = (r & 7) * 64;
    wsplit_tile(W1, w1h, w1l, F_DIM, H_DIM, H_DIM / 128, e, n0, k0, tile);
  } else if (b < 2560) {
    int i = b - 1536;
    int e = i >> 8, r = i & 255;
    int n0 = (r >> 4) * 64, k0 = (r & 15) * 64;
    wsplit_tile(W2, w2h, w2l, H_DIM, H_DIM, H_DIM / 128, e, n0, k0, tile);
  } else {
    int i = b - 2560;
    int e = i >> 7, r = i & 127;
    int n0 = (r >> 4) * 64, k0 = (r & 15) * 64;
    wsplit_tile(W3, w3h, w3l, H_DIM, N_DIM, N_DIM / 128, e, n0, k0, tile);
  }
}

// ---------- grouped GEMM: 64x128 tile, 4 waves (2x2), 2-buffer (R4-proven loop) ----------
// Operands pre-tiled -> every stage instruction is one contiguous 1-KB burst.
// Bank swizzle kept: LDS linear dest; SOURCE chunk permuted within each tile by
// the involution lch=(c&3)^((c>>3)&3); read side applies the same XOR
// (R7-verified: SQ_LDS_BANK_CONFLICT == 0).
// split product: ah*bh + ah*bl + al*bh (~2^-16 relative)
template <int K, int NOUT, bool RELU, bool FINAL>
__launch_bounds__(256, 3)
__global__ void k_gemm(const short* __restrict__ Ah, const short* __restrict__ Al,
                       const short* __restrict__ Bh, const short* __restrict__ Bl,
                       const float* __restrict__ bias,
                       short* __restrict__ Ch, short* __restrict__ Cl,
                       float* __restrict__ outF, const int* __restrict__ idx,
                       const int4* __restrict__ slots) {
  constexpr int NT  = NOUT / 128;
  constexpr int KT  = K / 32;
  constexpr int KTN = NOUT / 32;   // k-tiles of the NEXT layer (for tiled h write)
  constexpr int NWG = NSLOT * NT;
  int wg   = (blockIdx.x & 7) * (NWG / 8) + (blockIdx.x >> 3);
  int slot = wg / NT;
  int nt   = wg % NT;
  int4 s = slots[slot];
  int rows = s.y;
  if (rows == 0) return;
  int row0 = s.x, e = s.z, row_end = row0 + rows;   // row0 is 64-aligned
  int ncol0 = nt * 128;

  // per buffer (shorts): [Ah 64x32 @0][Al @2048][Bh 128x32 @4096][Bl @8192] = 24 KiB; x2 = 48 KiB
  __shared__ short lds[2][12288];

  int tid = threadIdx.x, wave = tid >> 6, ln = tid & 63;

  // tiled operand bases (row0 64-aligned; ncol0/128 == nt)
  size_t abase = (size_t)(row0 >> 6) * KT * 2048;
  size_t bbase = ((size_t)e * NT + nt) * KT * 4096;
  auto swz = [](int c) { return (c >> 2) * 32 + ((c & 3) ^ ((c >> 3) & 3)) * 8; };
  const short* srcb[6];
  srcb[0] = Ah + abase + swz(tid);
  srcb[1] = Al + abase + swz(tid);
  srcb[2] = Bh + bbase + swz(tid);
  srcb[3] = Bh + bbase + swz(tid + 256);
  srcb[4] = Bl + bbase + swz(tid);
  srcb[5] = Bl + bbase + swz(tid + 256);
  const int STR[6] = {2048, 2048, 4096, 4096, 4096, 4096};

  // LDS dest is wave-uniform base (+ lane*16 applied by HW) [m104/m108]
  int wbase = (tid & ~63) * 8;

  auto stage = [&](int buf, int kt) {
#pragma unroll
    for (int r = 0; r < 6; ++r)
      gload_lds16(srcb[r] + (size_t)STR[r] * kt, (void*)&lds[buf][r * 2048 + wbase]);
  };

  f32x4 acc[2][4] = {};
  int wr = wave >> 1, wcn = wave & 1;
  int tm = ln & 15, kg = ln >> 4;

  // read-side swizzled short-offsets (loop-invariant; R7-verified)
  int aoff[2], boff[4];
#pragma unroll
  for (int i = 0; i < 2; ++i) {
    int arow = wr * 32 + i * 16 + tm;
    aoff[i] = arow * 32 + (kg ^ ((arow >> 1) & 3)) * 8;
  }
#pragma unroll
  for (int j = 0; j < 4; ++j) {
    int brow = wcn * 64 + j * 16 + tm;
    boff[j] = brow * 32 + (kg ^ ((brow >> 1) & 3)) * 8;
  }

  stage(0, 0);
  __syncthreads();
  for (int ks = 0; ks < KT; ++ks) {
    int cb = ks & 1;
    if (ks + 1 < KT) stage(cb ^ 1, ks + 1);   // async prefetch during MFMA
    short8 ah[2], al[2], bh[4], bl[4];
#pragma unroll
    for (int i = 0; i < 2; ++i) {
      ah[i] = *(const short8*)&lds[cb][aoff[i]];
      al[i] = *(const short8*)&lds[cb][2048 + aoff[i]];
    }
#pragma unroll
    for (int j = 0; j < 4; ++j) {
      bh[j] = *(const short8*)&lds[cb][4096 + boff[j]];
      bl[j] = *(const short8*)&lds[cb][8192 + boff[j]];
    }
#pragma unroll
    for (int i = 0; i < 2; ++i)
#pragma unroll
      for (int j = 0; j < 4; ++j) {
        acc[i][j] = __builtin_amdgcn_mfma_f32_16x16x32_bf16(ah[i], bh[j], acc[i][j], 0, 0, 0);
        acc[i][j] = __builtin_amdgcn_mfma_f32_16x16x32_bf16(ah[i], bl[j], acc[i][j], 0, 0, 0);
        acc[i][j] = __builtin_amdgcn_mfma_f32_16x16x32_bf16(al[i], bh[j], acc[i][j], 0, 0, 0);
      }
    __syncthreads();   // drains vmcnt (prefetch landed) + protects buffer reuse
  }

  // epilogue: C/D layout col=lane&15, row=(lane>>4)*4+q  [m89-verified]
  int lcol = ln & 15;
  int lrow4 = (ln >> 4) * 4;
#pragma unroll
  for (int j = 0; j < 4; ++j) {
    int col = ncol0 + wcn * 64 + j * 16 + lcol;
    float bv = bias[(size_t)e * NOUT + col];
#pragma unroll
    for (int i = 0; i < 2; ++i) {
      int gr0 = row0 + wr * 32 + i * 16 + lrow4;
#pragma unroll
      for (int q = 0; q < 4; ++q) {
        int grow = gr0 + q;
        if (grow < row_end) {
          float x = acc[i][j][q] + bv;
          if (RELU) x = fmaxf(x, 0.0f);
          if (FINAL) {
            int token = idx[grow];
            outF[(size_t)token * NOUT + col] = x;
          } else {
            short h, l;
            split_bf(x, h, l);
            size_t hb = ((size_t)(grow >> 6) * KTN + (col >> 5)) * 2048 +
                        (size_t)(grow & 63) * 32 + (col & 31);
            Ch[hb] = h;
            Cl[hb] = l;
          }
        }
      }
    }
  }
}

extern "C" void kernel_launch(void* const* d_in, const int* in_sizes, int n_in,
                              void* d_out, int out_size, void* d_ws, size_t ws_size,
                              hipStream_t stream) {
  (void)in_sizes; (void)n_in; (void)out_size; (void)ws_size;
  const float* obs = (const float*)d_in[0];
  const float* W1  = (const float*)d_in[1];
  const float* b1  = (const float*)d_in[2];
  const float* W2  = (const float*)d_in[3];
  const float* b2  = (const float*)d_in[4];
  const float* W3  = (const float*)d_in[5];
  const float* b3  = (const float*)d_in[6];
  const int*   at  = (const int*)d_in[7];
  float* out = (float*)d_out;

  char* w = (char*)d_ws;
  auto carve = [&](size_t bytes) {
    char* p = w;
    w += (bytes + 255) & ~(size_t)255;
    return p;
  };
  int*  pos   = (int*)carve(NTOK * 4);
  int4* slots = (int4*)carve(NSLOT * 16);
  int*  idx   = (int*)carve(NTOK_PAD * 4);
  short* obsH = (short*)carve((size_t)NTOK_PAD * F_DIM * 2);
  short* obsL = (short*)carve((size_t)NTOK_PAD * F_DIM * 2);
  short* h1H  = (short*)carve((size_t)NTOK_PAD * H_DIM * 2);
  short* h1L  = (short*)carve((size_t)NTOK_PAD * H_DIM * 2);
  short* h2H  = (short*)carve((size_t)NTOK_PAD * H_DIM * 2);
  short* h2L  = (short*)carve((size_t)NTOK_PAD * H_DIM * 2);
  short* w1h  = (short*)carve((size_t)E_DIM * H_DIM * F_DIM * 2);
  short* w1l  = (short*)carve((size_t)E_DIM * H_DIM * F_DIM * 2);
  short* w2h  = (short*)carve((size_t)E_DIM * H_DIM * H_DIM * 2);
  short* w2l  = (short*)carve((size_t)E_DIM * H_DIM * H_DIM * 2);
  short* w3h  = (short*)carve((size_t)E_DIM * N_DIM * H_DIM * 2);
  short* w3l  = (short*)carve((size_t)E_DIM * N_DIM * H_DIM * 2);

  k_route<<<1, 1024, 0, stream>>>(at, pos, slots);
  k_prep<<<3072, 256, 0, stream>>>(obs, pos, idx, obsH, obsL,
                                   W1, w1h, w1l, W2, w2h, w2l, W3, w3h, w3l);

  k_gemm<F_DIM, H_DIM, true, false>
      <<<NSLOT * (H_DIM / 128), 256, 0, stream>>>(
          obsH, obsL, w1h, w1l, b1, h1H, h1L, nullptr, nullptr, slots);
  k_gemm<H_DIM, H_DIM, true, false>
      <<<NSLOT * (H_DIM / 128), 256, 0, stream>>>(
          h1H, h1L, w2h, w2l, b2, h2H, h2L, nullptr, nullptr, slots);
  k_gemm<H_DIM, N_DIM, false, true>
      <<<NSLOT * (N_DIM / 128), 256, 0, stream>>>(
          h2H, h2L, w3h, w3l, b3, nullptr, nullptr, out, idx, slots);
}